// Round 1
// baseline (254.363 us; speedup 1.0000x reference)
//
#include <hip/hip_runtime.h>
#include <hip/hip_bf16.h>

// Problem constants (fixed by the reference).
constexpr int T  = 4096;   // time / contraction dim (K)
constexpr int Bb = 8;      // batch
constexpr int C  = 512;    // channels (N)
constexpr int S  = 2048;   // groups (M)
constexpr int BC = Bb * C; // 4096, stride of a t-row in x and an s-row in out

typedef __bf16 bf16x8 __attribute__((ext_vector_type(8)));
typedef float  f32x16 __attribute__((ext_vector_type(16)));

__device__ inline __bf16 f2b(float f) {
    union { __hip_bfloat16 h; __bf16 b; } u;
    u.h = __float2bfloat16(f);   // RNE f32->bf16
    return u.b;
}

// out[0,b,c] = leftmost[c]
__global__ void left_fill(const float* __restrict__ left, float* __restrict__ out) {
    int i = blockIdx.x * blockDim.x + threadIdx.x;   // 0..BC-1
    if (i < BC) out[i] = left[i & (C - 1)];
}

// Per-b GEMM: D[s,c] = sum_t mask[b,t,s] * x[t,b,c], written to out[(s+1),b,c].
// Block = 256 threads = 4 waves (2x2), block tile 128(s) x 128(c),
// wave tile 64x64 = 2x2 fragments of v_mfma_f32_32x32x16_bf16.
// No LDS: fragments are loaded straight from global (coalesced 128B runs along
// s for mask, along c for x), converted fp32->bf16 in registers.
__global__ __launch_bounds__(256, 2) void ds_gemm(
    const float* __restrict__ x,
    const float* __restrict__ mask,
    float* __restrict__ out)
{
    const int bid = blockIdx.x;
    const int mt  = bid & 15;         // s-tile index (fastest -> mask panel stays on one XCD)
    const int nt  = (bid >> 4) & 3;   // c-tile index
    const int b   = bid >> 6;         // batch

    const int tid  = threadIdx.x;
    const int lane = tid & 63;
    const int wave = tid >> 6;        // 0..3
    const int wm = wave >> 1, wn = wave & 1;

    const int lm = lane & 31;         // row/col within a 32x32 fragment
    const int kg = lane >> 5;         // k-half select (0/1)

    const int s_w = mt * 128 + wm * 64;
    const int c_w = nt * 128 + wn * 64;

    const float* maskB = mask + (size_t)b * T * S;
    // A fragment base: element i of frag m2 is pa[i*S + m2*32]
    const float* pa = maskB + (size_t)(kg * 8) * S + (s_w + lm);
    // B fragment base: element i of frag n2 is pb[i*BC + n2*32]
    const float* pb = x + (size_t)(kg * 8) * BC + b * C + (c_w + lm);

    f32x16 acc[2][2] = {};
    bf16x8 Ac[2], Bc[2], An[2], Bn[2];

#define LOAD_FRAGS(Af, Bf, PA, PB)                                   \
    {                                                                \
        _Pragma("unroll") for (int m2 = 0; m2 < 2; ++m2) {           \
            _Pragma("unroll") for (int i = 0; i < 8; ++i)            \
                Af[m2][i] = f2b((PA)[(size_t)i * S + m2 * 32]);      \
        }                                                            \
        _Pragma("unroll") for (int n2 = 0; n2 < 2; ++n2) {           \
            _Pragma("unroll") for (int i = 0; i < 8; ++i)            \
                Bf[n2][i] = f2b((PB)[(size_t)i * BC + n2 * 32]);     \
        }                                                            \
    }

#define DO_MFMA(Af, Bf)                                              \
    {                                                                \
        _Pragma("unroll") for (int m2 = 0; m2 < 2; ++m2)             \
        _Pragma("unroll") for (int n2 = 0; n2 < 2; ++n2)             \
            acc[m2][n2] = __builtin_amdgcn_mfma_f32_32x32x16_bf16(   \
                Af[m2], Bf[n2], acc[m2][n2], 0, 0, 0);               \
    }

    // Prologue: fragments for t in [0,16)
    LOAD_FRAGS(Ac, Bc, pa, pb);

    // Each iteration consumes 32 t (two K=16 fragment sets), register ping-pong.
    for (int t0 = 0; t0 < T - 32; t0 += 32) {
        LOAD_FRAGS(An, Bn, pa + (size_t)16 * S, pb + (size_t)16 * BC);
        DO_MFMA(Ac, Bc);
        pa += (size_t)32 * S;
        pb += (size_t)32 * BC;
        LOAD_FRAGS(Ac, Bc, pa, pb);
        DO_MFMA(An, Bn);
    }
    // Epilogue: pa/pb now at t = T-32; Ac holds [T-32, T-16).
    LOAD_FRAGS(An, Bn, pa + (size_t)16 * S, pb + (size_t)16 * BC);
    DO_MFMA(Ac, Bc);
    DO_MFMA(An, Bn);

#undef LOAD_FRAGS
#undef DO_MFMA

    // Epilogue store. C/D layout (HW-verified): col = lane&31,
    // row = (r&3) + 8*(r>>2) + 4*(lane>>5), r in [0,16).
    float* outp = out + BC;   // skip the leftmost row
#pragma unroll
    for (int m2 = 0; m2 < 2; ++m2) {
#pragma unroll
        for (int n2 = 0; n2 < 2; ++n2) {
#pragma unroll
            for (int r = 0; r < 16; ++r) {
                const int row  = (r & 3) + 8 * (r >> 2) + 4 * kg;
                const int srow = s_w + m2 * 32 + row;
                const int ccol = c_w + n2 * 32 + lm;
                outp[(size_t)srow * BC + b * C + ccol] = acc[m2][n2][r];
            }
        }
    }
}

extern "C" void kernel_launch(void* const* d_in, const int* in_sizes, int n_in,
                              void* d_out, int out_size, void* d_ws, size_t ws_size,
                              hipStream_t stream) {
    const float* x    = (const float*)d_in[0];  // [T,B,C] fp32
    const float* mask = (const float*)d_in[1];  // [B,T,S] fp32
    // d_in[2] = size_of_groups (int64) — unused by the 'average' reference path
    const float* left = (const float*)d_in[3];  // [1,1,C] fp32
    float* out = (float*)d_out;                 // [S+1,B,C] fp32

    left_fill<<<BC / 256, 256, 0, stream>>>(left, out);
    ds_gemm<<<Bb * (S / 128) * (C / 128), 256, 0, stream>>>(x, mask, out);
}